// Round 1
// 461.261 us; speedup vs baseline: 1.1917x; 1.1917x over previous
//
#include <hip/hip_runtime.h>

typedef __bf16 bf16x8 __attribute__((ext_vector_type(8)));
typedef float f32x4 __attribute__((ext_vector_type(4)));

__device__ inline unsigned short f2bf(float f) {
  unsigned int u = __float_as_uint(f);
  u = (u + 0x7FFFu + ((u >> 16) & 1u)) >> 16;
  return (unsigned short)u;
}

__device__ inline void gl_lds16(const void* g, void* l) {
  __builtin_amdgcn_global_load_lds(
      (__attribute__((address_space(1))) const void*)g,
      (__attribute__((address_space(3))) void*)l, 16, 0, 0);
}

// ---------------- fp32 -> bf16 conversion ----------------
__global__ __launch_bounds__(256) void cvt_f32_bf16(const float* __restrict__ in,
                                                    unsigned short* __restrict__ out,
                                                    int n4) {
  int i = blockIdx.x * 256 + threadIdx.x;
  if (i >= n4) return;
  const float4 v = ((const float4*)in)[i];
  ushort4 o;
  o.x = f2bf(v.x); o.y = f2bf(v.y); o.z = f2bf(v.z); o.w = f2bf(v.w);
  ((ushort4*)out)[i] = o;
}

// ---------------- 256x256 / BK=64 8-phase GEMM (T1+T2+T3+T4+T5) ----------
// C[M,N] = A[M,K] @ W[N,K]^T.  512 threads = 8 waves (2 M x 4 N), per-wave
// output 128x64.  LDS 128 KiB: 2 buffers x {A[256][64], B[256][64]} bf16,
// each half (128x64=16KB) stored as 16 x st_16x32 subtiles (1KB each) with
// XOR-bit5^bit9 swizzle applied via pre-swizzled global source + swizzled
// ds_read (both-sides involution).  Counted vmcnt(4) only at phases 4/8.
// MODE 0: bf16 out, fused QKV (W segment by m0>>12, Q scaled).  MODE 1: f32 out.
template <int MODE>
__global__ __launch_bounds__(512, 2) void gemm8(const unsigned short* __restrict__ A,
                                                const unsigned short* __restrict__ Wb,
                                                void* __restrict__ Cv,
                                                int N, int K, float qscale) {
  extern __shared__ char lds[];
  const int tid = threadIdx.x;
  const int w = tid >> 6, l = tid & 63;
  const int wr = w >> 2, wc = w & 3;  // 2 x 4 wave grid

  // bijective XCD swizzle (gridDim.x % 8 == 0 for all our launches)
  const int nbx = N >> 8;
  const int cpx = gridDim.x >> 3;
  const int bid = blockIdx.x;
  const int swz = (bid & 7) * cpx + (bid >> 3);
  const int by = swz / nbx, bx = swz % nbx;
  const int m0 = by << 8, n0 = bx << 8;

  const unsigned short* W = Wb;
  float scale = 1.0f;
  if (MODE == 0) {
    int seg = m0 >> 12;  // 0=Q,1=K,2=V (4096 rows each; 256 | 4096)
    W = Wb + (size_t)seg * 2048 * 2048;
    scale = (seg == 0) ? qscale : 1.0f;
  }

  // ---- staging addressing: wave w stages subtiles {2w,2w+1} of each half.
  // linear LDS dest (lane*16); global source pre-swizzled so that swizzled
  // reads recover row-major data.  col_l = ((l&3)*8) ^ (l>=32 ? 16 : 0)
  const int col_l = ((l & 3) * 8) ^ ((l >= 32) ? 16 : 0);
  const size_t rowA0 = (size_t)(m0 + w * 16 + (l >> 2)) * K + col_l;
  const size_t rowA1 = rowA0 + (size_t)128 * K;
  const size_t rowB0 = (size_t)(n0 + w * 16 + (l >> 2)) * K + col_l;
  const size_t rowB1 = rowB0 + (size_t)128 * K;
  const int stA = w * 2048;  // dest byte offset of subtile pair within a half

  // ---- fragment-read addressing (swizzled): logical L = (l&15)*64+(l>>4)*16,
  // stored at L ^ ((row&8)?32:0)
  const int Sread = ((l & 15) * 64 + (l >> 4) * 16) ^ ((l & 8) << 2);
  const int ldsAr = wr * 16384 + Sread;                // A-half of this wave
  const int ldsBr = 32768 + (wc >> 1) * 16384 + Sread; // B-half of this wave

  const f32x4 fz = {0.f, 0.f, 0.f, 0.f};
  f32x4 acc[8][4];
#pragma unroll
  for (int i = 0; i < 8; i++)
#pragma unroll
    for (int j = 0; j < 4; j++) acc[i][j] = fz;
  bf16x8 af[2][4], bfr[2][4];

#define STAGE_A(b, h, kb)                                                          \
  gl_lds16(A + ((h) ? rowA1 : rowA0) + (kb), lds + (b) * 65536 + (h) * 16384 + stA); \
  gl_lds16(A + ((h) ? rowA1 : rowA0) + (kb) + 32,                                  \
           lds + (b) * 65536 + (h) * 16384 + stA + 1024)

#define STAGE_B(b, h, kb)                                                  \
  gl_lds16(W + ((h) ? rowB1 : rowB0) + (kb),                               \
           lds + (b) * 65536 + 32768 + (h) * 16384 + stA);                 \
  gl_lds16(W + ((h) ? rowB1 : rowB0) + (kb) + 32,                          \
           lds + (b) * 65536 + 32768 + (h) * 16384 + stA + 1024)

#define LDA(b, qi)                                                                   \
  _Pragma("unroll") for (int i = 0; i < 4; ++i) {                                    \
    af[0][i] = *(const bf16x8*)(lds + (b) * 65536 + ldsAr + ((qi) * 4 + i) * 2048);  \
    af[1][i] =                                                                       \
        *(const bf16x8*)(lds + (b) * 65536 + ldsAr + ((qi) * 4 + i) * 2048 + 1024);  \
  }

#define LDB(b, qj)                                                                    \
  _Pragma("unroll") for (int j = 0; j < 2; ++j) {                                     \
    bfr[0][(qj) * 2 + j] = *(const bf16x8*)(lds + (b) * 65536 + ldsBr +               \
                                            ((wc & 1) * 4 + (qj) * 2 + j) * 2048);    \
    bfr[1][(qj) * 2 + j] = *(const bf16x8*)(lds + (b) * 65536 + ldsBr +               \
                                            ((wc & 1) * 4 + (qj) * 2 + j) * 2048 +    \
                                            1024);                                    \
  }

#define MM(qi, qj)                                                              \
  __builtin_amdgcn_s_setprio(1);                                                \
  _Pragma("unroll") for (int ks = 0; ks < 2; ++ks)                              \
      _Pragma("unroll") for (int i = 0; i < 4; ++i)                             \
          _Pragma("unroll") for (int j = 0; j < 2; ++j) acc[(qi) * 4 + i]       \
                                                           [(qj) * 2 + j] =     \
      __builtin_amdgcn_mfma_f32_16x16x32_bf16(                                  \
          af[ks][i], bfr[ks][(qj) * 2 + j], acc[(qi) * 4 + i][(qj) * 2 + j], 0, \
          0, 0);                                                                \
  __builtin_amdgcn_s_setprio(0)

#define BAR                      \
  __builtin_amdgcn_s_barrier(); \
  __builtin_amdgcn_sched_barrier(0)
#define WL0                                          \
  asm volatile("s_waitcnt lgkmcnt(0)" ::: "memory"); \
  __builtin_amdgcn_sched_barrier(0)
#define WV4                                         \
  asm volatile("s_waitcnt vmcnt(4)" ::: "memory"); \
  __builtin_amdgcn_sched_barrier(0)

  // ---- prologue: tile0 full -> buf0, tile1 B-halves -> buf1
  STAGE_A(0, 0, 0);
  STAGE_A(0, 1, 0);
  STAGE_B(0, 0, 0);
  STAGE_B(0, 1, 0);
  STAGE_B(1, 0, 64);
  STAGE_B(1, 1, 64);
  WV4;
  BAR;

  const int NT = K >> 6;
  const int NI = NT >> 1;
  for (int it = 0; it < NI; ++it) {
    const int t1k = (2 * it + 1) * 64;
    const int t2k = ((2 * it + 2) < NT ? (2 * it + 2) : 0) * 64;  // wrapped
    const int t3k = ((2 * it + 3) < NT ? (2 * it + 3) : 1) * 64;  // (uniform vmcnt)

    // ph1: buf0 quadrant (0,0); stage A-h0(t+1 -> buf1)
    LDA(0, 0);
    LDB(0, 0);
    STAGE_A(1, 0, t1k);
    BAR; WL0;
    MM(0, 0);
    BAR;
    // ph2: (0,1); stage A-h1(t+1 -> buf1)
    LDB(0, 1);
    STAGE_A(1, 1, t1k);
    BAR; WL0;
    MM(0, 1);
    BAR;
    // ph3: (1,1); stage B-h0(t+2 -> buf0)  [buf0 B reads done at ph2]
    LDA(0, 1);
    STAGE_B(0, 0, t2k);
    BAR; WL0;
    MM(1, 1);
    BAR;
    // ph4: (1,0) from regs; stage B-h1(t+2 -> buf0); certify buf1 arrival
    STAGE_B(0, 1, t2k);
    BAR;
    MM(1, 0);
    WV4;
    BAR;
    // ph5: buf1 quadrant (0,0); stage A-h0(t+2 -> buf0)  [buf0 A reads done ph3]
    LDA(1, 0);
    LDB(1, 0);
    STAGE_A(0, 0, t2k);
    BAR; WL0;
    MM(0, 0);
    BAR;
    // ph6: (0,1); stage A-h1(t+2 -> buf0)
    LDB(1, 1);
    STAGE_A(0, 1, t2k);
    BAR; WL0;
    MM(0, 1);
    BAR;
    // ph7: (1,1); stage B-h0(t+3 -> buf1)  [buf1 B reads done ph6]
    LDA(1, 1);
    STAGE_B(1, 0, t3k);
    BAR; WL0;
    MM(1, 1);
    BAR;
    // ph8: (1,0) from regs; stage B-h1(t+3 -> buf1); certify buf0 arrival
    STAGE_B(1, 1, t3k);
    BAR;
    MM(1, 0);
    WV4;
    BAR;
  }

  // ---- epilogue
  const int erow = m0 + wr * 128 + (l >> 4) * 4;
  const int ecol = n0 + wc * 64 + (l & 15);
  if (MODE == 0) {
    unsigned short* C = (unsigned short*)Cv;
#pragma unroll
    for (int i = 0; i < 8; i++)
#pragma unroll
      for (int j = 0; j < 4; j++)
#pragma unroll
        for (int r = 0; r < 4; r++)
          C[(size_t)(erow + i * 16 + r) * N + ecol + j * 16] =
              f2bf(acc[i][j][r] * scale);
  } else {
    float* C = (float*)Cv;
#pragma unroll
    for (int i = 0; i < 8; i++)
#pragma unroll
      for (int j = 0; j < 4; j++)
#pragma unroll
        for (int r = 0; r < 4; r++)
          C[(size_t)(erow + i * 16 + r) * N + ecol + j * 16] = acc[i][j][r];
  }
#undef STAGE_A
#undef STAGE_B
#undef LDA
#undef LDB
#undef MM
#undef BAR
#undef WL0
#undef WV4
}

// ---------------- V transpose: [B,S,H*HD] -> [B,H,HD,S] ----------------
__global__ __launch_bounds__(256) void transpose_v(const unsigned short* __restrict__ Vb,
                                                   unsigned short* __restrict__ Vt) {
  __shared__ unsigned short tile[32][33];
  const int bh = blockIdx.z;
  const int s0 = blockIdx.x * 32, d0 = blockIdx.y * 32;
  const int tx = threadIdx.x & 31, ty = threadIdx.x >> 5;
  const int b = bh >> 4, h = bh & 15;
  for (int i = 0; i < 4; i++) {
    int s = s0 + ty + i * 8;
    tile[ty + i * 8][tx] = Vb[(size_t)(b * 2048 + s) * 2048 + h * 128 + d0 + tx];
  }
  __syncthreads();
  for (int i = 0; i < 4; i++) {
    int d = d0 + ty + i * 8;
    Vt[(size_t)(bh * 128 + d) * 2048 + s0 + tx] = tile[tx][ty + i * 8];
  }
}

// ---------------- causal flash attention, no-max softmax ----------------
__global__ __launch_bounds__(256) void flash_attn(const unsigned short* __restrict__ Qb,
                                                  const unsigned short* __restrict__ Kb,
                                                  const unsigned short* __restrict__ Vt,
                                                  unsigned short* __restrict__ Ob) {
  __shared__ __align__(16) unsigned short lsK[8192];
  __shared__ __align__(16) unsigned short lsV[8192];
  __shared__ __align__(16) unsigned short lsP[4096];
  const int h = blockIdx.x, b = blockIdx.y;
  const int tile = 31 - blockIdx.z;  // heavy first
  const int q0 = tile * 64;
  const int tid = threadIdx.x;
  const int w = tid >> 6, l = tid & 63;
  const int lm = l & 15, lk = l >> 4;

  bf16x8 qf[4];
  {
    const unsigned short* qr = Qb + (size_t)(b * 2048 + q0 + w * 16 + lm) * 2048 + h * 128;
    for (int dc = 0; dc < 4; dc++) qf[dc] = *(const bf16x8*)&qr[dc * 32 + lk * 8];
  }

  const f32x4 fz = {0.f, 0.f, 0.f, 0.f};
  float l_r[4] = {0.f, 0.f, 0.f, 0.f};
  f32x4 oacc[8];
  for (int jd = 0; jd < 8; jd++) oacc[jd] = fz;

  const int nkt = tile + 1;
  unsigned short* Pw = lsP + w * 1024;

  for (int kti = 0; kti < nkt; kti++) {
    const int kt = kti * 64;
    for (int iss = 0; iss < 4; iss++)
      gl_lds16(Kb + (size_t)(b * 2048 + kt + w * 16 + lm) * 2048 + h * 128 + (iss * 4 + lk) * 8,
               lsK + (w * 16 + iss * 4) * 128);
    for (int t = 0; t < 2; t++) {
      int dg = w * 2 + t;
      for (int c = 0; c < 2; c++)
        gl_lds16(Vt + (size_t)((b * 16 + h) * 128 + dg * 16 + lm) * 2048 + kt + (c * 4 + lk) * 8,
                 lsV + (dg * 8 + c * 4) * 128);
    }
    __syncthreads();

    f32x4 s[4];
    for (int jn = 0; jn < 4; jn++) s[jn] = fz;
    for (int jn = 0; jn < 4; jn++)
      for (int dc = 0; dc < 4; dc++) {
        bf16x8 kf = *(const bf16x8*)&lsK[(jn * 16 + dc * 4) * 128 + l * 8];
        s[jn] = __builtin_amdgcn_mfma_f32_16x16x32_bf16(qf[dc], kf, s[jn], 0, 0, 0);
      }

    const int diag = (kt == q0);
    for (int jn = 0; jn < 4; jn++) {
      int kcol = kt + jn * 16 + lm;
      for (int r = 0; r < 4; r++) {
        int qrow = q0 + w * 16 + lk * 4 + r;
        float p = (diag && kcol > qrow) ? 0.0f : __expf(s[jn][r]);
        s[jn][r] = p;
        l_r[r] += p;
      }
    }

    for (int jn = 0; jn < 4; jn++)
      for (int r = 0; r < 4; r++)
        Pw[(jn * 2 + (lm >> 3)) * 128 + (lk * 4 + r) * 8 + (lm & 7)] = f2bf(s[jn][r]);

    for (int c = 0; c < 2; c++) {
      bf16x8 pf = *(const bf16x8*)&Pw[c * 512 + l * 8];
      for (int jd = 0; jd < 8; jd++) {
        bf16x8 vf = *(const bf16x8*)&lsV[(jd * 8 + c * 4) * 128 + l * 8];
        oacc[jd] = __builtin_amdgcn_mfma_f32_16x16x32_bf16(pf, vf, oacc[jd], 0, 0, 0);
      }
    }
    __syncthreads();
  }

  for (int r = 0; r < 4; r++)
    for (int off = 1; off < 16; off <<= 1) l_r[r] += __shfl_xor(l_r[r], off, 64);

  for (int jd = 0; jd < 8; jd++) {
    int dcol = h * 128 + jd * 16 + lm;
    for (int r = 0; r < 4; r++) {
      size_t idx = (size_t)(b * 2048 + q0 + w * 16 + lk * 4 + r) * 2048 + dcol;
      Ob[idx] = f2bf(oacc[jd][r] / l_r[r]);
    }
  }
}

extern "C" void kernel_launch(void* const* d_in, const int* in_sizes, int n_in,
                              void* d_out, int out_size, void* d_ws, size_t ws_size,
                              hipStream_t stream) {
  const float* q  = (const float*)d_in[0];
  const float* k  = (const float*)d_in[1];
  const float* v  = (const float*)d_in[2];
  const float* wq = (const float*)d_in[3];
  const float* wk = (const float*)d_in[4];
  const float* wv = (const float*)d_in[5];
  const float* wo = (const float*)d_in[6];
  float* out = (float*)d_out;

  static bool attr_done = false;
  if (!attr_done) {
    hipFuncSetAttribute((const void*)gemm8<0>,
                        hipFuncAttributeMaxDynamicSharedMemorySize, 131072);
    hipFuncSetAttribute((const void*)gemm8<1>,
                        hipFuncAttributeMaxDynamicSharedMemorySize, 131072);
    attr_done = true;
  }

  const size_t SD = (size_t)4096 * 2048;
  const size_t DD = (size_t)2048 * 2048;
  unsigned short* ws  = (unsigned short*)d_ws;
  unsigned short* qb  = ws;            // A-stack: q,k,v contiguous
  unsigned short* kb  = qb + SD;
  unsigned short* vb  = kb + SD;
  unsigned short* wqb = vb + SD;       // W-stack: wq,wk,wv contiguous
  unsigned short* wkb = wqb + DD;
  unsigned short* wvb = wkb + DD;
  unsigned short* wob = wvb + DD;
  unsigned short* Qb  = wob + DD;      // C-stack: Q,K,V contiguous
  unsigned short* Kb  = Qb + SD;
  unsigned short* Vb  = Kb + SD;
  unsigned short* Vt  = qb;            // reuse qb after QKV gemm
  unsigned short* Ob  = kb;            // reuse kb after QKV gemm

  cvt_f32_bf16<<<8192, 256, 0, stream>>>(q,  qb,  (int)(SD / 4));
  cvt_f32_bf16<<<8192, 256, 0, stream>>>(k,  kb,  (int)(SD / 4));
  cvt_f32_bf16<<<8192, 256, 0, stream>>>(v,  vb,  (int)(SD / 4));
  cvt_f32_bf16<<<4096, 256, 0, stream>>>(wq, wqb, (int)(DD / 4));
  cvt_f32_bf16<<<4096, 256, 0, stream>>>(wk, wkb, (int)(DD / 4));
  cvt_f32_bf16<<<4096, 256, 0, stream>>>(wv, wvb, (int)(DD / 4));
  cvt_f32_bf16<<<4096, 256, 0, stream>>>(wo, wob, (int)(DD / 4));

  // fused QKV projection: M=12288 stacked -> 48x8 = 384 blocks (256^2 tiles)
  gemm8<0><<<dim3(384), 512, 131072, stream>>>(qb, wqb, (void*)Qb, 2048, 2048,
                                               0.08838834764831845f);

  transpose_v<<<dim3(64, 4, 32), 256, 0, stream>>>(Vb, Vt);

  flash_attn<<<dim3(16, 2, 32), 256, 0, stream>>>(Qb, Kb, Vt, Ob);

  // output projection: M=4096 -> 16x8 = 128 blocks (256^2 tiles)
  gemm8<1><<<dim3(128), 512, 131072, stream>>>(Ob, wob, (void*)out, 2048, 2048,
                                               1.0f);
}